// Round 1
// 619.612 us; speedup vs baseline: 1.2181x; 1.2181x over previous
//
#include <hip/hip_runtime.h>
#include <hip/hip_bf16.h>

// Problem constants: E=8 experts, H=1024, F=4096, TOK=16384, TPE=2048.
// Workspace layout (bytes), total 288 MiB:
//   [0,   32M)  xb    : x as bf16            (16384 x 1024)
//   [32M, 96M)  w1t   : w1^T as bf16         (E, 4096, 1024)  (N,K)
//   [96M,160M)  w2t   : w2^T as bf16         (E, 1024, 4096)  (N,K)
//   [160M,288M) inter : gelu(x@w1) as bf16   (E, 2048, 4096)

typedef __attribute__((ext_vector_type(8))) short short8;
typedef __attribute__((ext_vector_type(4))) float floatx4;

static __device__ __forceinline__ ushort f2bf(float f) {
  __hip_bfloat16 h = __float2bfloat16(f);
  return *(ushort*)&h;
}

// ===================== prep (unchanged, known-good) =========================

static __device__ __forceinline__ int swz(int n, int o) {
  return o ^ (n & 7) ^ ((n >> 3) & 7);
}

template<int K, int N>
static __device__ __forceinline__ void tpose_tile(const float* __restrict__ in,
                                                  __hip_bfloat16* __restrict__ out,
                                                  ushort* lds, int e, int nt, int kt) {
  const size_t eoff = (size_t)e * K * N;
  const int n0 = nt * 128, k0 = kt * 64;
  const int t = threadIdx.x;
  const int j = t & 15;
  const int g = t >> 4;   // 0..15
  const int o = g >> 1;   // 0..7  k-octet (rows k0+8o .. k0+8o+7)
  const int h = g & 1;    // 0..1  n-half
  const float* src = in + eoff + (size_t)(k0 + 8 * o) * N + n0 + h * 64 + 4 * j;
  float4 v[8];
#pragma unroll
  for (int r = 0; r < 8; ++r)
    v[r] = *(const float4*)(src + (size_t)r * N);
#pragma unroll
  for (int i = 0; i < 4; ++i) {
    const int n = h * 64 + 4 * j + i;
    union { short8 s8; ushort u[8]; } p;
#pragma unroll
    for (int r = 0; r < 8; ++r)
      p.u[r] = f2bf(((const float*)&v[r])[i]);
    *(short8*)(lds + n * 64 + swz(n, o) * 8) = p.s8;
  }
  __syncthreads();
  const int c = t & 7;     // k-chunk
  const int r0 = t >> 3;   // 0..31 row within pass
#pragma unroll
  for (int p = 0; p < 4; ++p) {
    const int n = p * 32 + r0;
    short8 u = *(const short8*)(lds + n * 64 + swz(n, c) * 8);
    *(short8*)(out + eoff + (size_t)(n0 + n) * K + k0 + 8 * c) = u;
  }
}

static __device__ __forceinline__ void cvt_part(const float* __restrict__ x,
                                                __hip_bfloat16* __restrict__ xb, int b) {
  const int t = threadIdx.x;
  const float4* src = (const float4*)x + (size_t)b * 2048 + t;
  ushort4* dst = (ushort4*)xb + (size_t)b * 2048 + t;
#pragma unroll
  for (int u = 0; u < 8; ++u) {
    float4 v = src[u * 256];
    ushort4 q;
    q.x = f2bf(v.x); q.y = f2bf(v.y); q.z = f2bf(v.z); q.w = f2bf(v.w);
    dst[u * 256] = q;
  }
}

__global__ __launch_bounds__(256) void prep(const float* __restrict__ x,
                                            const float* __restrict__ w1,
                                            const float* __restrict__ w2,
                                            __hip_bfloat16* __restrict__ xb,
                                            __hip_bfloat16* __restrict__ w1t,
                                            __hip_bfloat16* __restrict__ w2t) {
  __shared__ __align__(16) ushort lds[128 * 64];
  const int b = blockIdx.x;
  if (b < 2048) {
    cvt_part(x, xb, b);
  } else if (b < 6144) {
    const int bb = b - 2048;  // e*512 + kt*32 + nt
    tpose_tile<1024, 4096>(w1, w1t, lds, bb >> 9, bb & 31, (bb >> 5) & 15);
  } else {
    const int bb = b - 6144;  // e*512 + kt*8 + nt
    tpose_tile<4096, 1024>(w2, w2t, lds, bb >> 9, bb & 7, (bb >> 3) & 63);
  }
}

// ============== 256x256 8-phase counted-vmcnt bf16 GEMM =====================
// C = A @ Bt^T per expert. A: (E,M,K) bf16 rm; Bt: (E,N,K) bf16 rm (K contig).
// 512 threads = 8 waves (2M x 4N), per-wave output 128x64, BK=64.
// LDS 128 KiB: As/Bs each [2 buf][2 khalf][256 rows][32 k] bf16 (16KB regions).
// Swizzle: 16B chunk of (row r, chunk q) stored at slot q ^ ((r>>1)&3) --
// applied on the *global source* (linear global_load_lds dest) and on reads.
// Schedule per K-tile kt (buffer C=kt&1), phases:
//   p1: ds A[0..3]@klo + B[0..3]@klo | stage A-hi(kt+1)->buf C^1 | 16 MFMA
//   p2: ds A[4..7]@klo (B reuse)     | stage B-hi(kt+1)->buf C^1 | 16 MFMA
//   p3: ds A[0..3]@khi + B[0..3]@khi | stage A-lo(kt+2)->buf C   | 16 MFMA
//   p4: ds A[4..7]@khi               | stage B-lo(kt+2)->buf C   | 16 MFMA
//       then s_waitcnt vmcnt(4) (tail: 0) + barrier.
// Liveness: klo regions of buf C are dead after p2 (p3/p4 read only khi), so
// staging kt+2 into them at p3/p4 is safe (p2-end barrier publishes all reads).
// vmcnt(4) at tile end leaves exactly {A-lo,B-lo}(kt+2) in flight and
// guarantees all of kt+1 has landed. Never a vmcnt(0) drain in steady state.

#define GLDS16(src, dst)                                                       \
  __builtin_amdgcn_global_load_lds(                                            \
      (const __attribute__((address_space(1))) void*)(src),                    \
      (__attribute__((address_space(3))) void*)(dst), 16, 0, 0)

#define WAITVM(n) asm volatile("s_waitcnt vmcnt(" #n ")" ::: "memory")

#define MFMA16(a, b, c) __builtin_amdgcn_mfma_f32_16x16x32_bf16(a, b, c, 0, 0, 0)

static __device__ __forceinline__ void barsync() {
  asm volatile("" ::: "memory");
  __builtin_amdgcn_sched_barrier(0);
  __builtin_amdgcn_s_barrier();
  __builtin_amdgcn_sched_barrier(0);
  asm volatile("" ::: "memory");
}

template<int C>
static __device__ __forceinline__ void ktile(
    int kt, int nt, int t,
    const __hip_bfloat16* __restrict__ aread, const __hip_bfloat16* __restrict__ bread,
    const __hip_bfloat16* __restrict__ Asrc0, const __hip_bfloat16* __restrict__ Asrc1,
    const __hip_bfloat16* __restrict__ Bsrc0, const __hip_bfloat16* __restrict__ Bsrc1,
    __hip_bfloat16* As, __hip_bfloat16* Bs,
    floatx4 (&acc)[8][4]) {
  const int kc1 = (kt + 1) * 64 + 32;  // k-hi of tile kt+1 (elements)
  const int kc2 = (kt + 2) * 64;       // k-lo of tile kt+2
  const bool st1 = (kt + 1 < nt);
  const bool st2 = (kt + 2 < nt);
  short8 af[4], bf[4];

  // ---------------- phase 1 ----------------
#pragma unroll
  for (int i = 0; i < 4; ++i)
    af[i] = *(const short8*)(aread + (C * 2 + 0) * 8192 + i * 512);
#pragma unroll
  for (int j = 0; j < 4; ++j)
    bf[j] = *(const short8*)(bread + (C * 2 + 0) * 8192 + j * 512);
  if (st1) {
    __hip_bfloat16* d = As + ((C ^ 1) * 2 + 1) * 8192;
    GLDS16(Asrc0 + kc1, d + t * 8);
    GLDS16(Asrc1 + kc1, d + 4096 + t * 8);
  }
  barsync();
  __builtin_amdgcn_s_setprio(1);
#pragma unroll
  for (int i = 0; i < 4; ++i)
#pragma unroll
    for (int j = 0; j < 4; ++j)
      acc[i][j] = MFMA16(af[i], bf[j], acc[i][j]);
  __builtin_amdgcn_s_setprio(0);
  barsync();

  // ---------------- phase 2 ----------------
#pragma unroll
  for (int i = 0; i < 4; ++i)
    af[i] = *(const short8*)(aread + (C * 2 + 0) * 8192 + 2048 + i * 512);
  if (st1) {
    __hip_bfloat16* d = Bs + ((C ^ 1) * 2 + 1) * 8192;
    GLDS16(Bsrc0 + kc1, d + t * 8);
    GLDS16(Bsrc1 + kc1, d + 4096 + t * 8);
  }
  barsync();
  __builtin_amdgcn_s_setprio(1);
#pragma unroll
  for (int i = 0; i < 4; ++i)
#pragma unroll
    for (int j = 0; j < 4; ++j)
      acc[i + 4][j] = MFMA16(af[i], bf[j], acc[i + 4][j]);
  __builtin_amdgcn_s_setprio(0);
  barsync();

  // ---------------- phase 3 ----------------
#pragma unroll
  for (int i = 0; i < 4; ++i)
    af[i] = *(const short8*)(aread + (C * 2 + 1) * 8192 + i * 512);
#pragma unroll
  for (int j = 0; j < 4; ++j)
    bf[j] = *(const short8*)(bread + (C * 2 + 1) * 8192 + j * 512);
  if (st2) {
    __hip_bfloat16* d = As + (C * 2 + 0) * 8192;
    GLDS16(Asrc0 + kc2, d + t * 8);
    GLDS16(Asrc1 + kc2, d + 4096 + t * 8);
  }
  barsync();
  __builtin_amdgcn_s_setprio(1);
#pragma unroll
  for (int i = 0; i < 4; ++i)
#pragma unroll
    for (int j = 0; j < 4; ++j)
      acc[i][j] = MFMA16(af[i], bf[j], acc[i][j]);
  __builtin_amdgcn_s_setprio(0);
  barsync();

  // ---------------- phase 4 ----------------
#pragma unroll
  for (int i = 0; i < 4; ++i)
    af[i] = *(const short8*)(aread + (C * 2 + 1) * 8192 + 2048 + i * 512);
  if (st2) {
    __hip_bfloat16* d = Bs + (C * 2 + 0) * 8192;
    GLDS16(Bsrc0 + kc2, d + t * 8);
    GLDS16(Bsrc1 + kc2, d + 4096 + t * 8);
  }
  barsync();
  __builtin_amdgcn_s_setprio(1);
#pragma unroll
  for (int i = 0; i < 4; ++i)
#pragma unroll
    for (int j = 0; j < 4; ++j)
      acc[i + 4][j] = MFMA16(af[i], bf[j], acc[i + 4][j]);
  __builtin_amdgcn_s_setprio(0);
  if (st2) { WAITVM(4); } else { WAITVM(0); }
  barsync();
}

template<bool GELU, typename OutT>
__global__ __launch_bounds__(512, 2) void gemm8(
    const __hip_bfloat16* __restrict__ A, const __hip_bfloat16* __restrict__ Bt,
    OutT* __restrict__ C, int M, int N, int K) {
  __shared__ __align__(16) __hip_bfloat16 lds[65536];  // 128 KiB
  __hip_bfloat16* As = lds;
  __hip_bfloat16* Bs = lds + 32768;

  const int e = blockIdx.z;
  A  += (size_t)e * M * K;
  Bt += (size_t)e * N * K;
  C  += (size_t)e * M * N;

  // T1: bijective XCD swizzle. XCD grid 2(m) x 4(n); per-expert nwg % 8 == 0.
  const int MT = M >> 8, NT = N >> 8;
  const int lin = blockIdx.x;
  const int xcd = lin & 7;
  const int idx = lin >> 3;
  const int mh = MT >> 1, nq = NT >> 2;
  const int mt  = (xcd >> 2) * mh + idx % mh;
  const int nti = (xcd & 3) * nq + idx / mh;
  const int m0 = mt << 8, n0 = nti << 8;

  const int t = threadIdx.x;
  const int lane = t & 63;
  const int l16 = lane & 15;
  const int quad = lane >> 4;
  const int w = t >> 6;
  const int wr = w >> 2;  // 0..1 (M)
  const int wc = w & 3;   // 0..3 (N)
  // read-side swizzled 16B slot offset (per-thread constant, see header proof)
  const int sx = (quad ^ ((l16 >> 1) & 3)) * 8;

  const __hip_bfloat16* aread = As + (wr * 128 + l16) * 32 + sx;
  const __hip_bfloat16* bread = Bs + (wc * 64 + l16) * 32 + sx;

  // stage-side lane constants: slot u*512+t -> row, pre-swizzled global chunk
  const int r0s = t >> 2;
  const int q0s = ((t & 3) ^ ((r0s >> 1) & 3)) * 8;
  const int r1s = r0s + 128;
  const int q1s = ((t & 3) ^ ((r1s >> 1) & 3)) * 8;
  const __hip_bfloat16* Asrc0 = A  + (size_t)(m0 + r0s) * K + q0s;
  const __hip_bfloat16* Asrc1 = A  + (size_t)(m0 + r1s) * K + q1s;
  const __hip_bfloat16* Bsrc0 = Bt + (size_t)(n0 + r0s) * K + q0s;
  const __hip_bfloat16* Bsrc1 = Bt + (size_t)(n0 + r1s) * K + q1s;

  const int nt = K >> 6;
  floatx4 acc[8][4] = {};

  // prologue: tile0 (all 4 halves) + tile1 k-lo; then counted wait.
  GLDS16(Asrc0 + 0,  As + t * 8);            GLDS16(Asrc1 + 0,  As + 4096 + t * 8);
  GLDS16(Bsrc0 + 0,  Bs + t * 8);            GLDS16(Bsrc1 + 0,  Bs + 4096 + t * 8);
  GLDS16(Asrc0 + 32, As + 8192 + t * 8);     GLDS16(Asrc1 + 32, As + 12288 + t * 8);
  GLDS16(Bsrc0 + 32, Bs + 8192 + t * 8);     GLDS16(Bsrc1 + 32, Bs + 12288 + t * 8);
  if (nt > 1) {
    GLDS16(Asrc0 + 64, As + 16384 + t * 8);  GLDS16(Asrc1 + 64, As + 20480 + t * 8);
    GLDS16(Bsrc0 + 64, Bs + 16384 + t * 8);  GLDS16(Bsrc1 + 64, Bs + 20480 + t * 8);
    WAITVM(4);
  } else {
    WAITVM(0);
  }
  barsync();

  for (int kt = 0; kt < nt; kt += 2) {
    ktile<0>(kt,     nt, t, aread, bread, Asrc0, Asrc1, Bsrc0, Bsrc1, As, Bs, acc);
    ktile<1>(kt + 1, nt, t, aread, bread, Asrc0, Asrc1, Bsrc0, Bsrc1, As, Bs, acc);
  }

  // Epilogue. C/D layout (verified m89): col = lane&15, row = quad*4 + reg.
  const int mrow = m0 + wr * 128 + quad * 4;
  const int ncol = n0 + wc * 64 + l16;
#pragma unroll
  for (int i = 0; i < 8; ++i) {
#pragma unroll
    for (int r = 0; r < 4; ++r) {
      OutT* crow = C + (size_t)(mrow + i * 16 + r) * N + ncol;
#pragma unroll
      for (int j = 0; j < 4; ++j) {
        float v = acc[i][j][r];
        if constexpr (GELU) {
          // tanh-gelu via exp: gelu(v) = v - v/(e^{2u}+1), u = 0.7978845608(v+0.044715v^3)
          const float u2 = 1.5957691216057308f * (v + 0.044715f * v * v * v);
          const float ex = __expf(u2);
          v = v - v * __builtin_amdgcn_rcpf(ex + 1.0f);
        }
        if constexpr (sizeof(OutT) == 2)
          crow[j * 16] = __float2bfloat16(v);
        else
          crow[j * 16] = v;
      }
    }
  }
}

extern "C" void kernel_launch(void* const* d_in, const int* in_sizes, int n_in,
                              void* d_out, int out_size, void* d_ws, size_t ws_size,
                              hipStream_t stream) {
  const float* x  = (const float*)d_in[0];   // (16384, 1024)
  const float* w1 = (const float*)d_in[1];   // (8, 1024, 4096)
  const float* w2 = (const float*)d_in[2];   // (8, 4096, 1024)
  float* out = (float*)d_out;                // (16384, 1024) fp32

  char* ws = (char*)d_ws;
  __hip_bfloat16* xb    = (__hip_bfloat16*)(ws);
  __hip_bfloat16* w1t   = (__hip_bfloat16*)(ws + (size_t)32 * 1024 * 1024);
  __hip_bfloat16* w2t   = (__hip_bfloat16*)(ws + (size_t)96 * 1024 * 1024);
  __hip_bfloat16* inter = (__hip_bfloat16*)(ws + (size_t)160 * 1024 * 1024);

  // 1) prep: x->bf16, w1->w1t (bf16, transposed), w2->w2t (bf16, transposed)
  prep<<<10240, 256, 0, stream>>>(x, w1, w2, xb, w1t, w2t);
  // 2) inter = gelu(x_e @ w1_e) : M=2048, N=4096, K=1024 per expert
  //    grid.x = (M/256)*(N/256) = 8*16 = 128 per expert
  gemm8<true, __hip_bfloat16>
      <<<dim3(128, 1, 8), 512, 0, stream>>>(xb, w1t, inter, 2048, 4096, 1024);
  // 3) out = inter_e @ w2_e : M=2048, N=1024, K=4096 per expert; 8*4 = 32 wg
  gemm8<false, float>
      <<<dim3(32, 1, 8), 512, 0, stream>>>(inter, w2t, out, 2048, 1024, 4096);
}